// Round 24
// baseline (66.255 us; speedup 1.0000x reference)
//
#include <hip/hip_runtime.h>
#include <hip/hip_bf16.h>

typedef __hip_bfloat16 bf16;
typedef __attribute__((ext_vector_type(8))) short bf16x8;    // 8 bf16 = 4 VGPR
typedef __attribute__((ext_vector_type(4))) float f32x4;
typedef __attribute__((ext_vector_type(16))) float f32x16;

#define MFMA16(a, b, c) __builtin_amdgcn_mfma_f32_16x16x32_bf16((a), (b), (c), 0, 0, 0)
#define MFMA32(a, b, c) __builtin_amdgcn_mfma_f32_32x32x16_bf16((a), (b), (c), 0, 0, 0)

// ---- constants ----
// B=2, S=2048, D=768, HD=64, NH=12, NKV=4, GROUPS=3, WINDOW=384, theta=1e4, eps=1e-6
// R24 = R21 best config (63.7us) + XCD-aware swizzle on k_attn's grid (T1):
// 768 blocks = 8 (kv,b) groups x 96; chunked bijective remap pins each group
// (which shares 512KB K/V) to one XCD's L2 -> kills cross-XCD K/V re-fetch.
// Swizzle is bijective => correctness-invariant.

__device__ __forceinline__ void st4bf(bf16* p, float4 v) {
    bf16 t[4];
    t[0] = __float2bfloat16(v.x); t[1] = __float2bfloat16(v.y);
    t[2] = __float2bfloat16(v.z); t[3] = __float2bfloat16(v.w);
    *reinterpret_cast<uint2*>(p) = *reinterpret_cast<const uint2*>(t);
}

// ============ Kernel 0: fp32->bf16 conversion + RoPE table ============
__global__ __launch_bounds__(256) void k_prep(
    const float* __restrict__ hs, const float* __restrict__ qw,
    const float* __restrict__ kw, const float* __restrict__ vw,
    const float* __restrict__ ow,
    bf16* __restrict__ hsb, bf16* __restrict__ qwb, bf16* __restrict__ kwb,
    bf16* __restrict__ vwb, bf16* __restrict__ owb, float2* __restrict__ tab)
{
    const int bid = blockIdx.x, tid = threadIdx.x;
    const float* src; bf16* dst; int rel;
    if (bid < 3072)      { src = hs; dst = hsb; rel = bid; }
    else if (bid < 3648) { src = qw; dst = qwb; rel = bid - 3072; }
    else if (bid < 3840) { src = kw; dst = kwb; rel = bid - 3648; }
    else if (bid < 4032) { src = vw; dst = vwb; rel = bid - 3840; }
    else if (bid < 4608) { src = ow; dst = owb; rel = bid - 4032; }
    else {
        int i = (bid - 4608) * 256 + tid;
        int f = i & 31;
        float ang = (float)(i >> 5) * expf(-(float)f * 0.28782313662425572f);
        float sn, cs; sincosf(ang, &sn, &cs);
        tab[i] = make_float2(cs, sn);
        return;
    }
    int i = (rel * 256 + tid) * 4;
    float4 v = *reinterpret_cast<const float4*>(src + i);
    st4bf(dst + i, v);
}

// ================= Kernel 1: MFMA QKV GEMM + RMSNorm + RoPE (R21) ================
__global__ __launch_bounds__(256) void k_qkv(
    const bf16* __restrict__ hsb, const bf16* __restrict__ qwb,
    const bf16* __restrict__ kwb, const bf16* __restrict__ vwb,
    const float* __restrict__ qln, const float* __restrict__ kln,
    const float2* __restrict__ tab,
    bf16* __restrict__ qo, bf16* __restrict__ ko, bf16* __restrict__ vto)
{
    __shared__ bf16 As[2][64 * 72];
    __shared__ bf16 Bs[2][64 * 72];
    const int tid = threadIdx.x;
    const int w = tid >> 6, l = tid & 63;
    const int lm = l & 15, lg = l >> 4;
    const int m0 = blockIdx.x * 64;
    const int nblk = blockIdx.y;

    const bf16* wsrc; int wrow0, kind, head;
    if (nblk < 12)      { wsrc = qwb; wrow0 = nblk * 64;        kind = 0; head = nblk; }
    else if (nblk < 16) { wsrc = kwb; wrow0 = (nblk - 12) * 64; kind = 1; head = nblk - 12; }
    else                { wsrc = vwb; wrow0 = (nblk - 16) * 64; kind = 2; head = nblk - 16; }

    const int sr = tid >> 2, sc = (tid & 3) * 16;
    const bf16* aptr = hsb  + (size_t)(m0 + sr) * 768 + sc;
    const bf16* bptr = wsrc + (size_t)(wrow0 + sr) * 768 + sc;

    bf16x8 rA0 = *(const bf16x8*)(aptr);
    bf16x8 rA1 = *(const bf16x8*)(aptr + 8);
    bf16x8 rA2 = *(const bf16x8*)(bptr);
    bf16x8 rA3 = *(const bf16x8*)(bptr + 8);
    bf16x8 rB0 = *(const bf16x8*)(aptr + 64);
    bf16x8 rB1 = *(const bf16x8*)(aptr + 72);
    bf16x8 rB2 = *(const bf16x8*)(bptr + 64);
    bf16x8 rB3 = *(const bf16x8*)(bptr + 72);

    f32x4 acc[4] = {};
    for (int t = 0; t < 12; ++t) {
        const int p = t & 1;
        *(bf16x8*)(&As[p][sr * 72 + sc])     = rA0;
        *(bf16x8*)(&As[p][sr * 72 + sc + 8]) = rA1;
        *(bf16x8*)(&Bs[p][sr * 72 + sc])     = rA2;
        *(bf16x8*)(&Bs[p][sr * 72 + sc + 8]) = rA3;
        __syncthreads();
        rA0 = rB0; rA1 = rB1; rA2 = rB2; rA3 = rB3;
        if (t < 10) {
            const int off = (t + 2) * 64;
            rB0 = *(const bf16x8*)(aptr + off);
            rB1 = *(const bf16x8*)(aptr + off + 8);
            rB2 = *(const bf16x8*)(bptr + off);
            rB3 = *(const bf16x8*)(bptr + off + 8);
        }
        #pragma unroll
        for (int kk = 0; kk < 2; ++kk) {
            bf16x8 af = *(const bf16x8*)(&As[p][(w * 16 + lm) * 72 + kk * 32 + lg * 8]);
            #pragma unroll
            for (int ct = 0; ct < 4; ++ct) {
                bf16x8 bfr = *(const bf16x8*)(&Bs[p][(ct * 16 + lm) * 72 + kk * 32 + lg * 8]);
                acc[ct] = MFMA16(af, bfr, acc[ct]);
            }
        }
    }

    const int b  = m0 >> 11;
    const int s0 = m0 & 2047;

    if (kind == 2) {  // V: write TRANSPOSED [b][kv][d][s]
        bf16* base = vto + (size_t)(b * 4 + head) * 64 * 2048;
        #pragma unroll
        for (int r = 0; r < 4; ++r) {
            const int s = s0 + w * 16 + lg * 4 + r;
            #pragma unroll
            for (int ct = 0; ct < 4; ++ct)
                base[(size_t)(ct * 16 + lm) * 2048 + s] = __float2bfloat16(acc[ct][r]);
        }
        return;
    }

    const float* ln = (kind == 0) ? qln : kln;
    const float qscl = (kind == 0) ? 0.18033688011117042f : 1.0f;  // 0.125*log2(e) in Q
    float lw[4];
    #pragma unroll
    for (int ct = 0; ct < 4; ++ct) lw[ct] = ln[ct * 16 + lm] * qscl;

    bf16* base = (kind == 0) ? qo + ((size_t)(b * 12 + head) * 2048 + s0) * 64
                             : ko + ((size_t)(b * 4  + head) * 2048 + s0) * 64;
    #pragma unroll
    for (int r = 0; r < 4; ++r) {
        float n0 = acc[0][r], n1 = acc[1][r], n2 = acc[2][r], n3 = acc[3][r];
        float ss = n0 * n0 + n1 * n1 + n2 * n2 + n3 * n3;
        ss += __shfl_xor(ss, 1);
        ss += __shfl_xor(ss, 2);
        ss += __shfl_xor(ss, 4);
        ss += __shfl_xor(ss, 8);
        float rms = rsqrtf(ss * (1.0f / 64.0f) + 1e-6f);
        n0 *= rms * lw[0]; n1 *= rms * lw[1]; n2 *= rms * lw[2]; n3 *= rms * lw[3];
        const int row = w * 16 + lg * 4 + r;
        const float2* tp = tab + (size_t)(s0 + row) * 32;
        float2 t0 = tp[lm], t1 = tp[lm + 16];
        bf16* dst = base + (size_t)row * 64;
        dst[lm]      = __float2bfloat16(n0 * t0.x - n2 * t0.y);
        dst[lm + 16] = __float2bfloat16(n1 * t1.x - n3 * t1.y);
        dst[lm + 32] = __float2bfloat16(n2 * t0.x + n0 * t0.y);
        dst[lm + 48] = __float2bfloat16(n3 * t1.x + n1 * t1.y);
    }
}

// ================= Kernel 2: swapped-QK 32x32 attention (R13 + XCD swizzle) ======
// 1D grid of 768 blocks; physical bid -> logical via chunked XCD map:
// logical = (bid&7)*96 + (bid>>3). Logical order: ((b*4+kv)*3 + hh)*32 + qb,
// so each 96-logical chunk (= one XCD) shares one kv-head's K/V.
__global__ __launch_bounds__(128) void k_attn(
    const bf16* __restrict__ qi, const bf16* __restrict__ ki,
    const bf16* __restrict__ vti, bf16* __restrict__ ao)
{
    __shared__ bf16 Ks[2][64 * 72];   // [k_local][d]
    __shared__ bf16 Vs[2][64 * 72];   // [d][k_local]
    const int tid = threadIdx.x;
    const int w = tid >> 6, l = tid & 63;
    const int p = l >> 5, c31 = l & 31;

    const int bid = blockIdx.x;
    const int logical = (bid & 7) * 96 + (bid >> 3);
    const int qb = logical & 31;
    const int g  = logical >> 5;          // ((b*4+kv)*3 + hh)
    const int hh = g % 3;
    const int gkvb = g / 3;               // b*4+kv
    const int kv = gkvb & 3;
    const int b  = gkvb >> 2;
    const int h  = kv * 3 + hh;

    const int q0 = qb * 64;
    const int qw0 = q0 + w * 32;
    const int q_g = qw0 + c31;

    const bf16* qrow = qi + ((size_t)((b * 12 + h) * 2048 + q_g)) * 64 + p * 8;
    bf16x8 qf0 = *(const bf16x8*)(qrow);
    bf16x8 qf1 = *(const bf16x8*)(qrow + 16);
    bf16x8 qf2 = *(const bf16x8*)(qrow + 32);
    bf16x8 qf3 = *(const bf16x8*)(qrow + 48);

    f32x16 oacc0 = {}, oacc1 = {};
    float m_ = -INFINITY, l_ = 0.f;

    const int sr = tid >> 1, sc = (tid & 1) * 32;
    const bf16* kgb = ki  + (size_t)(b * 4 + kv) * 2048 * 64;
    const bf16* vgb = vti + (size_t)(b * 4 + kv) * 64 * 2048;

    const int kb_lo = (qb > 6) ? (qb - 6) : 0;
    bf16x8 rk[4], rv[4];
    {
        const bf16* kp = kgb + (size_t)(kb_lo * 64 + sr) * 64 + sc;
        const bf16* vp = vgb + (size_t)sr * 2048 + kb_lo * 64 + sc;
        #pragma unroll
        for (int j = 0; j < 4; ++j) {
            rk[j] = *(const bf16x8*)(kp + j * 8);
            rv[j] = *(const bf16x8*)(vp + j * 8);
        }
    }

    for (int kb = kb_lo; kb <= qb; ++kb) {
        const int pb = (kb - kb_lo) & 1;
        const int k0 = kb * 64;

        #pragma unroll
        for (int j = 0; j < 4; ++j) {
            *(bf16x8*)(&Ks[pb][sr * 72 + sc + j * 8]) = rk[j];
            *(bf16x8*)(&Vs[pb][sr * 72 + sc + j * 8]) = rv[j];
        }
        __syncthreads();
        if (kb < qb) {
            const bf16* kp = kgb + (size_t)(k0 + 64 + sr) * 64 + sc;
            const bf16* vp = vgb + (size_t)sr * 2048 + k0 + 64 + sc;
            #pragma unroll
            for (int j = 0; j < 4; ++j) {
                rk[j] = *(const bf16x8*)(kp + j * 8);
                rv[j] = *(const bf16x8*)(vp + j * 8);
            }
        }

        f32x16 s0 = {}, s1 = {};
        {
            const bf16* kbase = &Ks[pb][c31 * 72 + p * 8];
            s0 = MFMA32(*(const bf16x8*)(kbase),      qf0, s0);
            s0 = MFMA32(*(const bf16x8*)(kbase + 16), qf1, s0);
            s0 = MFMA32(*(const bf16x8*)(kbase + 32), qf2, s0);
            s0 = MFMA32(*(const bf16x8*)(kbase + 48), qf3, s0);
            const bf16* kbase1 = kbase + 32 * 72;
            s1 = MFMA32(*(const bf16x8*)(kbase1),      qf0, s1);
            s1 = MFMA32(*(const bf16x8*)(kbase1 + 16), qf1, s1);
            s1 = MFMA32(*(const bf16x8*)(kbase1 + 32), qf2, s1);
            s1 = MFMA32(*(const bf16x8*)(kbase1 + 48), qf3, s1);
        }

        const bool need_mask = (64 * kb + 63 > qw0) || (64 * kb <= qw0 - 353);
        if (need_mask) {
            #pragma unroll
            for (int r = 0; r < 16; ++r) {
                int kl = (r & 3) + 8 * (r >> 2) + 4 * p;
                int kg0 = k0 + kl, kg1 = k0 + 32 + kl;
                bool ok0 = (kg0 <= q_g) && (kg0 > q_g - 384);
                bool ok1 = (kg1 <= q_g) && (kg1 > q_g - 384);
                s0[r] = ok0 ? s0[r] : -INFINITY;
                s1[r] = ok1 ? s1[r] : -INFINITY;
            }
        }

        float tmax = s0[0];
        #pragma unroll
        for (int r = 1; r < 16; ++r) tmax = fmaxf(tmax, s0[r]);
        #pragma unroll
        for (int r = 0; r < 16; ++r) tmax = fmaxf(tmax, s1[r]);
        tmax = fmaxf(tmax, __shfl_xor(tmax, 32));

        float mnew = fmaxf(m_, tmax);
        float scale, rs = 0.f;
        if (mnew > -INFINITY) {
            scale = exp2f(m_ - mnew);
            #pragma unroll
            for (int r = 0; r < 16; ++r) { s0[r] = exp2f(s0[r] - mnew); rs += s0[r]; }
            #pragma unroll
            for (int r = 0; r < 16; ++r) { s1[r] = exp2f(s1[r] - mnew); rs += s1[r]; }
        } else {
            scale = 1.f;
            #pragma unroll
            for (int r = 0; r < 16; ++r) { s0[r] = 0.f; s1[r] = 0.f; }
        }
        m_ = mnew;
        rs += __shfl_xor(rs, 32);
        l_ = l_ * scale + rs;
        #pragma unroll
        for (int r = 0; r < 16; ++r) { oacc0[r] *= scale; oacc1[r] *= scale; }

        bf16x8 paf[4];
        #pragma unroll
        for (int kt = 0; kt < 2; ++kt) {
            unsigned pk[8];
            #pragma unroll
            for (int i = 0; i < 8; ++i) {
                float lo = (kt == 0) ? s0[2 * i] : s1[2 * i];
                float hi = (kt == 0) ? s0[2 * i + 1] : s1[2 * i + 1];
                bf16 blo = __float2bfloat16(lo), bhi = __float2bfloat16(hi);
                pk[i] = ((unsigned)*(unsigned short*)&bhi << 16) | (unsigned)*(unsigned short*)&blo;
            }
            unsigned x[8];
            #pragma unroll
            for (int i = 0; i < 8; ++i) x[i] = (unsigned)__shfl_xor((int)pk[i], 32);
            #pragma unroll
            for (int s = 0; s < 2; ++s) {
                union { int4 i4; bf16x8 v; } u;
                u.i4.x = p ? (int)x[4 * s + 2] : (int)pk[4 * s];
                u.i4.y = p ? (int)x[4 * s + 3] : (int)pk[4 * s + 1];
                u.i4.z = p ? (int)pk[4 * s + 2] : (int)x[4 * s];
                u.i4.w = p ? (int)pk[4 * s + 3] : (int)x[4 * s + 1];
                paf[kt * 2 + s] = u.v;
            }
        }

        {
            const bf16* vbase = &Vs[pb][c31 * 72 + p * 8];
            oacc0 = MFMA32(*(const bf16x8*)(vbase),      paf[0], oacc0);
            oacc0 = MFMA32(*(const bf16x8*)(vbase + 16), paf[1], oacc0);
            oacc0 = MFMA32(*(const bf16x8*)(vbase + 32), paf[2], oacc0);
            oacc0 = MFMA32(*(const bf16x8*)(vbase + 48), paf[3], oacc0);
            const bf16* vbase1 = vbase + 32 * 72;
            oacc1 = MFMA32(*(const bf16x8*)(vbase1),      paf[0], oacc1);
            oacc1 = MFMA32(*(const bf16x8*)(vbase1 + 16), paf[1], oacc1);
            oacc1 = MFMA32(*(const bf16x8*)(vbase1 + 32), paf[2], oacc1);
            oacc1 = MFMA32(*(const bf16x8*)(vbase1 + 48), paf[3], oacc1);
        }
        __syncthreads();
    }

    const float inv = 1.f / l_;
    bf16* dst = ao + ((size_t)(b * 2048 + q_g)) * 768 + h * 64;
    #pragma unroll
    for (int g2 = 0; g2 < 4; ++g2) {
        union { uint2 u2; bf16 t[4]; } o0, o1;
        #pragma unroll
        for (int e = 0; e < 4; ++e) {
            o0.t[e] = __float2bfloat16(oacc0[4 * g2 + e] * inv);
            o1.t[e] = __float2bfloat16(oacc1[4 * g2 + e] * inv);
        }
        *reinterpret_cast<uint2*>(dst + 8 * g2 + 4 * p)      = o0.u2;
        *reinterpret_cast<uint2*>(dst + 32 + 8 * g2 + 4 * p) = o1.u2;
    }
}

// ================= Kernel 3: MFMA output projection (R21) ========================
__global__ __launch_bounds__(256) void k_oproj(
    const bf16* __restrict__ A, const bf16* __restrict__ W, float* __restrict__ out)
{
    __shared__ bf16 As[2][64 * 72];
    __shared__ bf16 Bs[2][64 * 72];
    const int tid = threadIdx.x;
    const int w = tid >> 6, l = tid & 63;
    const int lm = l & 15, lg = l >> 4;
    const int m0 = blockIdx.x * 64, n0 = blockIdx.y * 64;

    const int sr = tid >> 2, sc = (tid & 3) * 16;
    const bf16* aptr = A + (size_t)(m0 + sr) * 768 + sc;
    const bf16* bptr = W + (size_t)(n0 + sr) * 768 + sc;

    bf16x8 rA0 = *(const bf16x8*)(aptr);
    bf16x8 rA1 = *(const bf16x8*)(aptr + 8);
    bf16x8 rA2 = *(const bf16x8*)(bptr);
    bf16x8 rA3 = *(const bf16x8*)(bptr + 8);
    bf16x8 rB0 = *(const bf16x8*)(aptr + 64);
    bf16x8 rB1 = *(const bf16x8*)(aptr + 72);
    bf16x8 rB2 = *(const bf16x8*)(bptr + 64);
    bf16x8 rB3 = *(const bf16x8*)(bptr + 72);

    f32x4 acc[4] = {};
    for (int t = 0; t < 12; ++t) {
        const int p = t & 1;
        *(bf16x8*)(&As[p][sr * 72 + sc])     = rA0;
        *(bf16x8*)(&As[p][sr * 72 + sc + 8]) = rA1;
        *(bf16x8*)(&Bs[p][sr * 72 + sc])     = rA2;
        *(bf16x8*)(&Bs[p][sr * 72 + sc + 8]) = rA3;
        __syncthreads();
        rA0 = rB0; rA1 = rB1; rA2 = rB2; rA3 = rB3;
        if (t < 10) {
            const int off = (t + 2) * 64;
            rB0 = *(const bf16x8*)(aptr + off);
            rB1 = *(const bf16x8*)(aptr + off + 8);
            rB2 = *(const bf16x8*)(bptr + off);
            rB3 = *(const bf16x8*)(bptr + off + 8);
        }
        #pragma unroll
        for (int kk = 0; kk < 2; ++kk) {
            bf16x8 af = *(const bf16x8*)(&As[p][(w * 16 + lm) * 72 + kk * 32 + lg * 8]);
            #pragma unroll
            for (int ct = 0; ct < 4; ++ct) {
                bf16x8 bfr = *(const bf16x8*)(&Bs[p][(ct * 16 + lm) * 72 + kk * 32 + lg * 8]);
                acc[ct] = MFMA16(af, bfr, acc[ct]);
            }
        }
    }

    #pragma unroll
    for (int r = 0; r < 4; ++r) {
        float* dst = out + (size_t)(m0 + w * 16 + lg * 4 + r) * 768 + n0;
        #pragma unroll
        for (int ct = 0; ct < 4; ++ct)
            dst[ct * 16 + lm] = acc[ct][r];
    }
}

extern "C" void kernel_launch(void* const* d_in, const int* in_sizes, int n_in,
                              void* d_out, int out_size, void* d_ws, size_t ws_size,
                              hipStream_t stream) {
    const float* hs  = (const float*)d_in[0];
    const float* qw  = (const float*)d_in[1];
    const float* kw  = (const float*)d_in[2];
    const float* vw  = (const float*)d_in[3];
    const float* ow  = (const float*)d_in[4];
    const float* qln = (const float*)d_in[5];
    const float* kln = (const float*)d_in[6];
    float* out = (float*)d_out;

    float2* tab  = (float2*)d_ws;
    bf16*   q_ws = (bf16*)(tab + 65536);
    bf16*   k_ws = q_ws + 3145728;
    bf16*   vt_ws= k_ws + 1048576;
    bf16*   x_ws = vt_ws + 1048576;    // hsb during k_qkv, attn output after
    bf16*   qwb  = x_ws + 3145728;
    bf16*   kwb  = qwb + 589824;
    bf16*   vwb  = kwb + 196608;
    bf16*   owb  = vwb + 196608;

    k_prep<<<dim3(4864), 256, 0, stream>>>(hs, qw, kw, vw, ow, x_ws, qwb, kwb, vwb, owb, tab);
    k_qkv<<<dim3(64, 20, 1), 256, 0, stream>>>(x_ws, qwb, kwb, vwb, qln, kln, tab, q_ws, k_ws, vt_ws);
    k_attn<<<dim3(768), 128, 0, stream>>>(q_ws, k_ws, vt_ws, x_ws);
    k_oproj<<<dim3(64, 12, 1), 256, 0, stream>>>(x_ws, owb, out);
}

// Round 25
// 63.562 us; speedup vs baseline: 1.0424x; 1.0424x over previous
//
#include <hip/hip_runtime.h>
#include <hip/hip_bf16.h>

typedef __hip_bfloat16 bf16;
typedef __attribute__((ext_vector_type(8))) short bf16x8;    // 8 bf16 = 4 VGPR
typedef __attribute__((ext_vector_type(4))) float f32x4;
typedef __attribute__((ext_vector_type(16))) float f32x16;

#define MFMA16(a, b, c) __builtin_amdgcn_mfma_f32_16x16x32_bf16((a), (b), (c), 0, 0, 0)
#define MFMA32(a, b, c) __builtin_amdgcn_mfma_f32_32x32x16_bf16((a), (b), (c), 0, 0, 0)

// ---- constants ----
// B=2, S=2048, D=768, HD=64, NH=12, NKV=4, GROUPS=3, WINDOW=384, theta=1e4, eps=1e-6
// FINAL: verified-best configuration (R16/R21/R23 = 63.7us, PASS x3, absmax 0.0039).
// - k_prep: fused fp32->bf16 conversion + RoPE cos/sin table
// - k_qkv/k_oproj: 64x64 MFMA GEMM, single-barrier dbuf, DEPTH-2 register prefetch
// - k_attn: swapped-QK 32x32 MFMA, in-register softmax (exp2-space, scale folded
//   into Q), staged dbuf K/V with reg prefetch, V stored transposed [b][kv][d][s]
// Measured-and-shelved: gload_lds (R10/R15), split-K (R18), GQA-merge (R12),
// KVBLK=128 macro (R22), permlane32_swap (R19/R20), XCD swizzle (R24: +2.6us).

__device__ __forceinline__ void st4bf(bf16* p, float4 v) {
    bf16 t[4];
    t[0] = __float2bfloat16(v.x); t[1] = __float2bfloat16(v.y);
    t[2] = __float2bfloat16(v.z); t[3] = __float2bfloat16(v.w);
    *reinterpret_cast<uint2*>(p) = *reinterpret_cast<const uint2*>(t);
}

// ============ Kernel 0: fp32->bf16 conversion + RoPE table ============
__global__ __launch_bounds__(256) void k_prep(
    const float* __restrict__ hs, const float* __restrict__ qw,
    const float* __restrict__ kw, const float* __restrict__ vw,
    const float* __restrict__ ow,
    bf16* __restrict__ hsb, bf16* __restrict__ qwb, bf16* __restrict__ kwb,
    bf16* __restrict__ vwb, bf16* __restrict__ owb, float2* __restrict__ tab)
{
    const int bid = blockIdx.x, tid = threadIdx.x;
    const float* src; bf16* dst; int rel;
    if (bid < 3072)      { src = hs; dst = hsb; rel = bid; }
    else if (bid < 3648) { src = qw; dst = qwb; rel = bid - 3072; }
    else if (bid < 3840) { src = kw; dst = kwb; rel = bid - 3648; }
    else if (bid < 4032) { src = vw; dst = vwb; rel = bid - 3840; }
    else if (bid < 4608) { src = ow; dst = owb; rel = bid - 4032; }
    else {
        int i = (bid - 4608) * 256 + tid;
        int f = i & 31;
        float ang = (float)(i >> 5) * expf(-(float)f * 0.28782313662425572f);
        float sn, cs; sincosf(ang, &sn, &cs);
        tab[i] = make_float2(cs, sn);
        return;
    }
    int i = (rel * 256 + tid) * 4;
    float4 v = *reinterpret_cast<const float4*>(src + i);
    st4bf(dst + i, v);
}

// ================= Kernel 1: MFMA QKV GEMM + RMSNorm + RoPE ======================
__global__ __launch_bounds__(256) void k_qkv(
    const bf16* __restrict__ hsb, const bf16* __restrict__ qwb,
    const bf16* __restrict__ kwb, const bf16* __restrict__ vwb,
    const float* __restrict__ qln, const float* __restrict__ kln,
    const float2* __restrict__ tab,
    bf16* __restrict__ qo, bf16* __restrict__ ko, bf16* __restrict__ vto)
{
    __shared__ bf16 As[2][64 * 72];
    __shared__ bf16 Bs[2][64 * 72];
    const int tid = threadIdx.x;
    const int w = tid >> 6, l = tid & 63;
    const int lm = l & 15, lg = l >> 4;
    const int m0 = blockIdx.x * 64;
    const int nblk = blockIdx.y;

    const bf16* wsrc; int wrow0, kind, head;
    if (nblk < 12)      { wsrc = qwb; wrow0 = nblk * 64;        kind = 0; head = nblk; }
    else if (nblk < 16) { wsrc = kwb; wrow0 = (nblk - 12) * 64; kind = 1; head = nblk - 12; }
    else                { wsrc = vwb; wrow0 = (nblk - 16) * 64; kind = 2; head = nblk - 16; }

    const int sr = tid >> 2, sc = (tid & 3) * 16;
    const bf16* aptr = hsb  + (size_t)(m0 + sr) * 768 + sc;
    const bf16* bptr = wsrc + (size_t)(wrow0 + sr) * 768 + sc;

    // depth-2 prologue: tile 0 -> rA, tile 1 -> rB
    bf16x8 rA0 = *(const bf16x8*)(aptr);
    bf16x8 rA1 = *(const bf16x8*)(aptr + 8);
    bf16x8 rA2 = *(const bf16x8*)(bptr);
    bf16x8 rA3 = *(const bf16x8*)(bptr + 8);
    bf16x8 rB0 = *(const bf16x8*)(aptr + 64);
    bf16x8 rB1 = *(const bf16x8*)(aptr + 72);
    bf16x8 rB2 = *(const bf16x8*)(bptr + 64);
    bf16x8 rB3 = *(const bf16x8*)(bptr + 72);

    f32x4 acc[4] = {};
    for (int t = 0; t < 12; ++t) {
        const int p = t & 1;
        *(bf16x8*)(&As[p][sr * 72 + sc])     = rA0;
        *(bf16x8*)(&As[p][sr * 72 + sc + 8]) = rA1;
        *(bf16x8*)(&Bs[p][sr * 72 + sc])     = rA2;
        *(bf16x8*)(&Bs[p][sr * 72 + sc + 8]) = rA3;
        __syncthreads();
        rA0 = rB0; rA1 = rB1; rA2 = rB2; rA3 = rB3;
        if (t < 10) {
            const int off = (t + 2) * 64;
            rB0 = *(const bf16x8*)(aptr + off);
            rB1 = *(const bf16x8*)(aptr + off + 8);
            rB2 = *(const bf16x8*)(bptr + off);
            rB3 = *(const bf16x8*)(bptr + off + 8);
        }
        #pragma unroll
        for (int kk = 0; kk < 2; ++kk) {
            bf16x8 af = *(const bf16x8*)(&As[p][(w * 16 + lm) * 72 + kk * 32 + lg * 8]);
            #pragma unroll
            for (int ct = 0; ct < 4; ++ct) {
                bf16x8 bfr = *(const bf16x8*)(&Bs[p][(ct * 16 + lm) * 72 + kk * 32 + lg * 8]);
                acc[ct] = MFMA16(af, bfr, acc[ct]);
            }
        }
    }

    const int b  = m0 >> 11;
    const int s0 = m0 & 2047;

    if (kind == 2) {  // V: write TRANSPOSED [b][kv][d][s]
        bf16* base = vto + (size_t)(b * 4 + head) * 64 * 2048;
        #pragma unroll
        for (int r = 0; r < 4; ++r) {
            const int s = s0 + w * 16 + lg * 4 + r;
            #pragma unroll
            for (int ct = 0; ct < 4; ++ct)
                base[(size_t)(ct * 16 + lm) * 2048 + s] = __float2bfloat16(acc[ct][r]);
        }
        return;
    }

    const float* ln = (kind == 0) ? qln : kln;
    const float qscl = (kind == 0) ? 0.18033688011117042f : 1.0f;  // 0.125*log2(e) in Q
    float lw[4];
    #pragma unroll
    for (int ct = 0; ct < 4; ++ct) lw[ct] = ln[ct * 16 + lm] * qscl;

    bf16* base = (kind == 0) ? qo + ((size_t)(b * 12 + head) * 2048 + s0) * 64
                             : ko + ((size_t)(b * 4  + head) * 2048 + s0) * 64;
    #pragma unroll
    for (int r = 0; r < 4; ++r) {
        float n0 = acc[0][r], n1 = acc[1][r], n2 = acc[2][r], n3 = acc[3][r];
        float ss = n0 * n0 + n1 * n1 + n2 * n2 + n3 * n3;
        ss += __shfl_xor(ss, 1);
        ss += __shfl_xor(ss, 2);
        ss += __shfl_xor(ss, 4);
        ss += __shfl_xor(ss, 8);
        float rms = rsqrtf(ss * (1.0f / 64.0f) + 1e-6f);
        n0 *= rms * lw[0]; n1 *= rms * lw[1]; n2 *= rms * lw[2]; n3 *= rms * lw[3];
        const int row = w * 16 + lg * 4 + r;
        const float2* tp = tab + (size_t)(s0 + row) * 32;
        float2 t0 = tp[lm], t1 = tp[lm + 16];
        bf16* dst = base + (size_t)row * 64;
        dst[lm]      = __float2bfloat16(n0 * t0.x - n2 * t0.y);
        dst[lm + 16] = __float2bfloat16(n1 * t1.x - n3 * t1.y);
        dst[lm + 32] = __float2bfloat16(n2 * t0.x + n0 * t0.y);
        dst[lm + 48] = __float2bfloat16(n3 * t1.x + n1 * t1.y);
    }
}

// ================= Kernel 2: swapped-QK 32x32 attention (R13) ====================
__global__ __launch_bounds__(128) void k_attn(
    const bf16* __restrict__ qi, const bf16* __restrict__ ki,
    const bf16* __restrict__ vti, bf16* __restrict__ ao)
{
    __shared__ bf16 Ks[2][64 * 72];   // [k_local][d]
    __shared__ bf16 Vs[2][64 * 72];   // [d][k_local]
    const int tid = threadIdx.x;
    const int w = tid >> 6, l = tid & 63;
    const int p = l >> 5, c31 = l & 31;
    const int qb = blockIdx.x, h = blockIdx.y, b = blockIdx.z;
    const int kv = h / 3;
    const int q0 = qb * 64;
    const int qw0 = q0 + w * 32;
    const int q_g = qw0 + c31;

    const bf16* qrow = qi + ((size_t)((b * 12 + h) * 2048 + q_g)) * 64 + p * 8;
    bf16x8 qf0 = *(const bf16x8*)(qrow);
    bf16x8 qf1 = *(const bf16x8*)(qrow + 16);
    bf16x8 qf2 = *(const bf16x8*)(qrow + 32);
    bf16x8 qf3 = *(const bf16x8*)(qrow + 48);

    f32x16 oacc0 = {}, oacc1 = {};
    float m_ = -INFINITY, l_ = 0.f;

    const int sr = tid >> 1, sc = (tid & 1) * 32;
    const bf16* kgb = ki  + (size_t)(b * 4 + kv) * 2048 * 64;
    const bf16* vgb = vti + (size_t)(b * 4 + kv) * 64 * 2048;

    const int kb_lo = (qb > 6) ? (qb - 6) : 0;
    bf16x8 rk[4], rv[4];
    {
        const bf16* kp = kgb + (size_t)(kb_lo * 64 + sr) * 64 + sc;
        const bf16* vp = vgb + (size_t)sr * 2048 + kb_lo * 64 + sc;
        #pragma unroll
        for (int j = 0; j < 4; ++j) {
            rk[j] = *(const bf16x8*)(kp + j * 8);
            rv[j] = *(const bf16x8*)(vp + j * 8);
        }
    }

    for (int kb = kb_lo; kb <= qb; ++kb) {
        const int pb = (kb - kb_lo) & 1;
        const int k0 = kb * 64;

        #pragma unroll
        for (int j = 0; j < 4; ++j) {
            *(bf16x8*)(&Ks[pb][sr * 72 + sc + j * 8]) = rk[j];
            *(bf16x8*)(&Vs[pb][sr * 72 + sc + j * 8]) = rv[j];
        }
        __syncthreads();
        if (kb < qb) {
            const bf16* kp = kgb + (size_t)(k0 + 64 + sr) * 64 + sc;
            const bf16* vp = vgb + (size_t)sr * 2048 + k0 + 64 + sc;
            #pragma unroll
            for (int j = 0; j < 4; ++j) {
                rk[j] = *(const bf16x8*)(kp + j * 8);
                rv[j] = *(const bf16x8*)(vp + j * 8);
            }
        }

        f32x16 s0 = {}, s1 = {};
        {
            const bf16* kbase = &Ks[pb][c31 * 72 + p * 8];
            s0 = MFMA32(*(const bf16x8*)(kbase),      qf0, s0);
            s0 = MFMA32(*(const bf16x8*)(kbase + 16), qf1, s0);
            s0 = MFMA32(*(const bf16x8*)(kbase + 32), qf2, s0);
            s0 = MFMA32(*(const bf16x8*)(kbase + 48), qf3, s0);
            const bf16* kbase1 = kbase + 32 * 72;
            s1 = MFMA32(*(const bf16x8*)(kbase1),      qf0, s1);
            s1 = MFMA32(*(const bf16x8*)(kbase1 + 16), qf1, s1);
            s1 = MFMA32(*(const bf16x8*)(kbase1 + 32), qf2, s1);
            s1 = MFMA32(*(const bf16x8*)(kbase1 + 48), qf3, s1);
        }

        const bool need_mask = (64 * kb + 63 > qw0) || (64 * kb <= qw0 - 353);
        if (need_mask) {
            #pragma unroll
            for (int r = 0; r < 16; ++r) {
                int kl = (r & 3) + 8 * (r >> 2) + 4 * p;
                int kg0 = k0 + kl, kg1 = k0 + 32 + kl;
                bool ok0 = (kg0 <= q_g) && (kg0 > q_g - 384);
                bool ok1 = (kg1 <= q_g) && (kg1 > q_g - 384);
                s0[r] = ok0 ? s0[r] : -INFINITY;
                s1[r] = ok1 ? s1[r] : -INFINITY;
            }
        }

        float tmax = s0[0];
        #pragma unroll
        for (int r = 1; r < 16; ++r) tmax = fmaxf(tmax, s0[r]);
        #pragma unroll
        for (int r = 0; r < 16; ++r) tmax = fmaxf(tmax, s1[r]);
        tmax = fmaxf(tmax, __shfl_xor(tmax, 32));

        float mnew = fmaxf(m_, tmax);
        float scale, rs = 0.f;
        if (mnew > -INFINITY) {
            scale = exp2f(m_ - mnew);
            #pragma unroll
            for (int r = 0; r < 16; ++r) { s0[r] = exp2f(s0[r] - mnew); rs += s0[r]; }
            #pragma unroll
            for (int r = 0; r < 16; ++r) { s1[r] = exp2f(s1[r] - mnew); rs += s1[r]; }
        } else {
            scale = 1.f;
            #pragma unroll
            for (int r = 0; r < 16; ++r) { s0[r] = 0.f; s1[r] = 0.f; }
        }
        m_ = mnew;
        rs += __shfl_xor(rs, 32);
        l_ = l_ * scale + rs;
        #pragma unroll
        for (int r = 0; r < 16; ++r) { oacc0[r] *= scale; oacc1[r] *= scale; }

        bf16x8 paf[4];
        #pragma unroll
        for (int kt = 0; kt < 2; ++kt) {
            unsigned pk[8];
            #pragma unroll
            for (int i = 0; i < 8; ++i) {
                float lo = (kt == 0) ? s0[2 * i] : s1[2 * i];
                float hi = (kt == 0) ? s0[2 * i + 1] : s1[2 * i + 1];
                bf16 blo = __float2bfloat16(lo), bhi = __float2bfloat16(hi);
                pk[i] = ((unsigned)*(unsigned short*)&bhi << 16) | (unsigned)*(unsigned short*)&blo;
            }
            unsigned x[8];
            #pragma unroll
            for (int i = 0; i < 8; ++i) x[i] = (unsigned)__shfl_xor((int)pk[i], 32);
            #pragma unroll
            for (int s = 0; s < 2; ++s) {
                union { int4 i4; bf16x8 v; } u;
                u.i4.x = p ? (int)x[4 * s + 2] : (int)pk[4 * s];
                u.i4.y = p ? (int)x[4 * s + 3] : (int)pk[4 * s + 1];
                u.i4.z = p ? (int)pk[4 * s + 2] : (int)x[4 * s];
                u.i4.w = p ? (int)pk[4 * s + 3] : (int)x[4 * s + 1];
                paf[kt * 2 + s] = u.v;
            }
        }

        {
            const bf16* vbase = &Vs[pb][c31 * 72 + p * 8];
            oacc0 = MFMA32(*(const bf16x8*)(vbase),      paf[0], oacc0);
            oacc0 = MFMA32(*(const bf16x8*)(vbase + 16), paf[1], oacc0);
            oacc0 = MFMA32(*(const bf16x8*)(vbase + 32), paf[2], oacc0);
            oacc0 = MFMA32(*(const bf16x8*)(vbase + 48), paf[3], oacc0);
            const bf16* vbase1 = vbase + 32 * 72;
            oacc1 = MFMA32(*(const bf16x8*)(vbase1),      paf[0], oacc1);
            oacc1 = MFMA32(*(const bf16x8*)(vbase1 + 16), paf[1], oacc1);
            oacc1 = MFMA32(*(const bf16x8*)(vbase1 + 32), paf[2], oacc1);
            oacc1 = MFMA32(*(const bf16x8*)(vbase1 + 48), paf[3], oacc1);
        }
        __syncthreads();
    }

    const float inv = 1.f / l_;
    bf16* dst = ao + ((size_t)(b * 2048 + q_g)) * 768 + h * 64;
    #pragma unroll
    for (int g = 0; g < 4; ++g) {
        union { uint2 u2; bf16 t[4]; } o0, o1;
        #pragma unroll
        for (int e = 0; e < 4; ++e) {
            o0.t[e] = __float2bfloat16(oacc0[4 * g + e] * inv);
            o1.t[e] = __float2bfloat16(oacc1[4 * g + e] * inv);
        }
        *reinterpret_cast<uint2*>(dst + 8 * g + 4 * p)      = o0.u2;
        *reinterpret_cast<uint2*>(dst + 32 + 8 * g + 4 * p) = o1.u2;
    }
}

// ================= Kernel 3: MFMA output projection (depth-2 prefetch) ===========
__global__ __launch_bounds__(256) void k_oproj(
    const bf16* __restrict__ A, const bf16* __restrict__ W, float* __restrict__ out)
{
    __shared__ bf16 As[2][64 * 72];
    __shared__ bf16 Bs[2][64 * 72];
    const int tid = threadIdx.x;
    const int w = tid >> 6, l = tid & 63;
    const int lm = l & 15, lg = l >> 4;
    const int m0 = blockIdx.x * 64, n0 = blockIdx.y * 64;

    const int sr = tid >> 2, sc = (tid & 3) * 16;
    const bf16* aptr = A + (size_t)(m0 + sr) * 768 + sc;
    const bf16* bptr = W + (size_t)(n0 + sr) * 768 + sc;

    bf16x8 rA0 = *(const bf16x8*)(aptr);
    bf16x8 rA1 = *(const bf16x8*)(aptr + 8);
    bf16x8 rA2 = *(const bf16x8*)(bptr);
    bf16x8 rA3 = *(const bf16x8*)(bptr + 8);
    bf16x8 rB0 = *(const bf16x8*)(aptr + 64);
    bf16x8 rB1 = *(const bf16x8*)(aptr + 72);
    bf16x8 rB2 = *(const bf16x8*)(bptr + 64);
    bf16x8 rB3 = *(const bf16x8*)(bptr + 72);

    f32x4 acc[4] = {};
    for (int t = 0; t < 12; ++t) {
        const int p = t & 1;
        *(bf16x8*)(&As[p][sr * 72 + sc])     = rA0;
        *(bf16x8*)(&As[p][sr * 72 + sc + 8]) = rA1;
        *(bf16x8*)(&Bs[p][sr * 72 + sc])     = rA2;
        *(bf16x8*)(&Bs[p][sr * 72 + sc + 8]) = rA3;
        __syncthreads();
        rA0 = rB0; rA1 = rB1; rA2 = rB2; rA3 = rB3;
        if (t < 10) {
            const int off = (t + 2) * 64;
            rB0 = *(const bf16x8*)(aptr + off);
            rB1 = *(const bf16x8*)(aptr + off + 8);
            rB2 = *(const bf16x8*)(bptr + off);
            rB3 = *(const bf16x8*)(bptr + off + 8);
        }
        #pragma unroll
        for (int kk = 0; kk < 2; ++kk) {
            bf16x8 af = *(const bf16x8*)(&As[p][(w * 16 + lm) * 72 + kk * 32 + lg * 8]);
            #pragma unroll
            for (int ct = 0; ct < 4; ++ct) {
                bf16x8 bfr = *(const bf16x8*)(&Bs[p][(ct * 16 + lm) * 72 + kk * 32 + lg * 8]);
                acc[ct] = MFMA16(af, bfr, acc[ct]);
            }
        }
    }

    #pragma unroll
    for (int r = 0; r < 4; ++r) {
        float* dst = out + (size_t)(m0 + w * 16 + lg * 4 + r) * 768 + n0;
        #pragma unroll
        for (int ct = 0; ct < 4; ++ct)
            dst[ct * 16 + lm] = acc[ct][r];
    }
}

extern "C" void kernel_launch(void* const* d_in, const int* in_sizes, int n_in,
                              void* d_out, int out_size, void* d_ws, size_t ws_size,
                              hipStream_t stream) {
    const float* hs  = (const float*)d_in[0];
    const float* qw  = (const float*)d_in[1];
    const float* kw  = (const float*)d_in[2];
    const float* vw  = (const float*)d_in[3];
    const float* ow  = (const float*)d_in[4];
    const float* qln = (const float*)d_in[5];
    const float* kln = (const float*)d_in[6];
    float* out = (float*)d_out;

    float2* tab  = (float2*)d_ws;
    bf16*   q_ws = (bf16*)(tab + 65536);
    bf16*   k_ws = q_ws + 3145728;
    bf16*   vt_ws= k_ws + 1048576;
    bf16*   x_ws = vt_ws + 1048576;    // hsb during k_qkv, attn output after
    bf16*   qwb  = x_ws + 3145728;
    bf16*   kwb  = qwb + 589824;
    bf16*   vwb  = kwb + 196608;
    bf16*   owb  = vwb + 196608;

    k_prep<<<dim3(4864), 256, 0, stream>>>(hs, qw, kw, vw, ow, x_ws, qwb, kwb, vwb, owb, tab);
    k_qkv<<<dim3(64, 20, 1), 256, 0, stream>>>(x_ws, qwb, kwb, vwb, qln, kln, tab, q_ws, k_ws, vt_ws);
    k_attn<<<dim3(32, 12, 2), 128, 0, stream>>>(q_ws, k_ws, vt_ws, x_ws);
    k_oproj<<<dim3(64, 12, 1), 256, 0, stream>>>(x_ws, owb, out);
}